// Round 1
// 318.298 us; speedup vs baseline: 1.0081x; 1.0081x over previous
//
#include <hip/hip_runtime.h>
#include <math.h>

// f32-rounded pi / 2pi (JAX weak-type f64->f32 folding): 0x40490FDB / 0x40C90FDB
#define PI_F        3.14159274101257324e0f
#define TWOPI_F     6.28318548202514648e0f
#define INV_TWOPI_F (1.0f / TWOPI_F)          // compile-time correctly-rounded f32

// dr2 < DR2_LT  <=>  __fsqrt_rn(dr2) < 0.05f, bit-exactly:
//   sqrt_rn monotone+correctly-rounded; c = 0.05f = 0x3D4CCCCD (odd mantissa),
//   boundary m = c - 2^-29 (tie at m rounds to even pred(c) < c), so
//   sqrt_rn(x) < c  <=>  x <= m^2.  m^2 = 0.0024999998882412921.. lies strictly
//   between pred(0.0025f)=0.0024999997112 and 0.0025f=0.0024999999441, so for
//   f32 x:  x <= m^2  <=>  x < 0.0025f.  One f32 compare replaces the whole
//   correctly-rounded-sqrt refine sequence.
#define DR2_LT      0.0025f

#define ROWS_PER_BLOCK 128
#define ROW_STRIDE     49                      // 48 floats + 1 pad (odd -> conflict-free reads)

// Exact replication of: m = fmod(dd, 2pi_f32); if (m<0) m += 2pi; dphi = m - pi;
// decision sqrt(deta^2+dphi^2) < 0.05 -- in PURE f32:
//  - q = truncf(dd * fl(1/2pi)). When q equals trunc(dd/2pi_f32), the fma
//    single-rounds the exact real remainder dd - q*2pi_f32, which is always
//    f32-representable (fmod representability) -> m is bit-exact = lax.rem.
//    The m<0 rounded += 2pi matches jnp.mod's adjust add exactly (same single
//    f32 add of the same exact remainder).
//  - q can misround (+/-1) only when dd/2pi_f32 is within ~2^-21 of an integer
//    (|dd|<~16 here: inputs are N(0,1)). In every such case both our dphi and
//    the reference's are within ~1e-5 of +/-pi, so dr2 ~ 9.87 >> 0.0025 and the
//    boolean decision is identical (we deliberately skip the m>=2pi re-fix:
//    it can only occur in this far-from-threshold regime).
//  - exact-zero remainder: fma yields +0, ref yields -0; both give dphi = -pi_f.
__device__ __forceinline__ int pair_close(float ei, float ej, float pi_, float pj) {
    float deta = __fsub_rn(ei, ej);
    float dd   = __fadd_rn(__fsub_rn(pi_, pj), PI_F);
    float q    = truncf(__fmul_rn(dd, INV_TWOPI_F));
    float m    = __fmaf_rn(q, -TWOPI_F, dd);   // exact remainder when q correct
    if (m < 0.0f) m = __fadd_rn(m, TWOPI_F);   // numpy floor-mod sign adjust (rounded, as ref)
    float dphi = __fsub_rn(m, PI_F);
    float dr2  = __fadd_rn(__fmul_rn(deta, deta), __fmul_rn(dphi, dphi));
    return dr2 < DR2_LT;
}

// Component-major row layout: float u (=4f+c) of a row lives at
//   rowbuf[rl*ROW_STRIDE + 12*(u&3) + (u>>2)].
// Writers (thread holding float4 f) store x/y/z/w at base+0/+12/+24/+36
// (compile-time ds_write offsets, consecutive lanes stride-1 dwords ->
// conflict-free). Readers use compile-time offsets off one base.
__device__ __forceinline__ float lds_at(const float* r, int u) {
    return r[12 * (u & 3) + (u >> 2)];
}

// Dup mask for group of N objects at offset OFF. Pair semantics (matches
// sentinel construction in the reference):
//   both inactive -> dr = 0      -> dup
//   one inactive  -> dr ~ 1e6    -> not dup
//   both active   -> exact f32 dR test on raw eta/phi
template <int OFF, int N>
__device__ __forceinline__ unsigned group_dup(const float* r) {
    float e[N], p[N];
    int   a[N];
#pragma unroll
    for (int k = 0; k < N; ++k) {
        int u = 3 * (OFF + k);
        a[k] = lds_at(r, u + 0) > 0.0f;
        e[k] = lds_at(r, u + 1);
        p[k] = lds_at(r, u + 2);
    }
    unsigned dup = 0;
#pragma unroll
    for (int j = 0; j < N - 1; ++j) {
        int d = 0;
#pragma unroll
        for (int i = j + 1; i < N; ++i) {
            int close = pair_close(e[i], e[j], p[i], p[j]);
            d |= (a[i] & a[j] & close) | ((a[i] | a[j]) ^ 1);
        }
        if (d) dup |= (1u << (OFF + j));
    }
    return dup;
}

// Block = 256 threads handling 128 rows.
//   load:  thread t loads float4 #(t+256i), i=0..5 (coalesced), keeps in regs,
//          scatters 4 scalars into the component-major LDS row (conflict-free).
//   mask:  threads 0..127 compute the 15-bit dup mask for their row from LDS,
//          expand to a 48-bit per-float mask, store to LDS.
//   store: thread t zeroes components of its registered float4s per the row's
//          expanded mask, coalesced float4 store.
// FULL specialization drops all bounds checks (7812 of 7813 blocks).
template <bool FULL>
__device__ __forceinline__ void block_body(
    const float4* __restrict__ in, float4* __restrict__ out, int B,
    float* rowbuf, unsigned long long* maskbuf) {
    const int t = threadIdx.x;
    const long long base4  = (long long)blockIdx.x * (ROWS_PER_BLOCK * 12);
    const long long total4 = (long long)B * 12;

    float4 v[6];
#pragma unroll
    for (int i = 0; i < 6; ++i) {
        long long g = base4 + t + 256 * i;
        if (FULL || g < total4) {
            v[i] = in[g];
            int local = t + 256 * i;
            int rl = local / 12;
            int f  = local - rl * 12;
            float* dstp = &rowbuf[rl * ROW_STRIDE + f];
            dstp[0] = v[i].x; dstp[12] = v[i].y; dstp[24] = v[i].z; dstp[36] = v[i].w;
        }
    }
    __syncthreads();

    if (t < ROWS_PER_BLOCK) {
        int row = blockIdx.x * ROWS_PER_BLOCK + t;
        unsigned dup = 0;
        if (FULL || row < B) {
            const float* r = rowbuf + t * ROW_STRIDE;
            dup  = group_dup<0, 6>(r);    // jets      (objects 0..5)
            dup |= group_dup<6, 3>(r);    // electrons (objects 6..8)
            dup |= group_dup<9, 3>(r);    // muons     (objects 9..11)
            dup |= group_dup<12, 3>(r);   // photons   (objects 12..14)
        }
        // expand object mask -> per-float mask (bit k = zero float k, k=0..44)
        unsigned long long fm = 0ull;
#pragma unroll
        for (int o = 0; o < 15; ++o)
            fm |= (unsigned long long)((dup >> o) & 1u) * (7ull << (3 * o));
        maskbuf[t] = fm;
    }
    __syncthreads();

#pragma unroll
    for (int i = 0; i < 6; ++i) {
        long long g = base4 + t + 256 * i;
        if (FULL || g < total4) {
            int local = t + 256 * i;
            int rl = local / 12;
            int f  = local - rl * 12;
            unsigned nib = (unsigned)(maskbuf[rl] >> (4 * f)) & 0xFu;
            float4 w = v[i];
            if (nib & 1u) w.x = 0.0f;
            if (nib & 2u) w.y = 0.0f;
            if (nib & 4u) w.z = 0.0f;
            if (nib & 8u) w.w = 0.0f;
            out[g] = w;
        }
    }
}

// 32-wave/CU cap means 4 blocks/CU max at 256 threads; (256,4) keeps the
// allocator at <=128 VGPR instead of (256,6)'s impossible 48-wave squeeze.
__global__ __launch_bounds__(256, 4) void dup_removal_kernel(
    const float4* __restrict__ in, float4* __restrict__ out, int B) {
    __shared__ float rowbuf[ROWS_PER_BLOCK * ROW_STRIDE];   // 24.5 KB
    __shared__ unsigned long long maskbuf[ROWS_PER_BLOCK];  // 1 KB

    const long long base4  = (long long)blockIdx.x * (ROWS_PER_BLOCK * 12);
    const long long total4 = (long long)B * 12;
    if (base4 + ROWS_PER_BLOCK * 12 <= total4)
        block_body<true>(in, out, B, rowbuf, maskbuf);
    else
        block_body<false>(in, out, B, rowbuf, maskbuf);
}

extern "C" void kernel_launch(void* const* d_in, const int* in_sizes, int n_in,
                              void* d_out, int out_size, void* d_ws, size_t ws_size,
                              hipStream_t stream) {
    const float4* x = (const float4*)d_in[0];
    float4* out = (float4*)d_out;
    int B = in_sizes[0] / 48;                            // rows of (16,3)
    int grid = (B + ROWS_PER_BLOCK - 1) / ROWS_PER_BLOCK;
    dup_removal_kernel<<<grid, 256, 0, stream>>>(x, out, B);
}